// Round 12
// baseline (168.560 us; speedup 1.0000x reference)
//
#include <hip/hip_runtime.h>
#include <hip/hip_bf16.h>
#include <math.h>

#define D_DIM   4096
#define B_ROWS  4096
#define K_CODES 256
#define MARGIN  3.0      // |approx d2 - exact d2| <= ~1.5 worst-case; 3.0 window
#define MT      16             // rows per gemm block
#define NSTEP   (D_DIM / 32)   // 128 k-steps of 32

// output layout (f32 elements)
#define IDX_OFF   (B_ROWS * D_DIM)                 // 16777216
#define PROBS_OFF (IDX_OFF + B_ROWS)               // 16781312
#define LOSS_OFF  (PROBS_OFF + B_ROWS * K_CODES)   // 17829888

typedef __bf16 bf16x8 __attribute__((ext_vector_type(8)));
typedef float  f32x4  __attribute__((ext_vector_type(4)));

// ws: d2[4096][256] f32 (4 MB) | cbsw[1M] ushort (2 MB) | cc[256] f64 | xxp[4096] f32
// cbsw layout (16x16x32 B-frag order): element (code k, col c) at ushort
//   (((c>>5)*16 + (k>>4))*64 + ((c>>3)&3)*16 + (k&15))*8 + (c&7)
// k-step L occupies [L*8192, L*8192+8192) ushorts; wave w, tile ct in {2w,2w+1}:
//   lane l reads 16 B at L*8192 + ct*512 + l*8
//   = B[k = L*32 + (l>>4)*8 + j][code = ct*16 + (l&15)]

static __device__ inline unsigned short f2bf(float f) {
    __hip_bfloat16 h = __float2bfloat16(f);
    return *reinterpret_cast<unsigned short*>(&h);
}

// ---------------------------------------------------------------------------
// prep_cb: one wave per codebook row. Swizzled bf16 codebook (16x16x32 frag
// order) + cc (f64 row sum of squares).
// ---------------------------------------------------------------------------
__global__ __launch_bounds__(64) void prep_cb(const float* __restrict__ cb,
                                              unsigned short* __restrict__ cbsw,
                                              double* __restrict__ cc) {
    const int lane = threadIdx.x & 63;
    const int k = blockIdx.x;                            // code 0..255
    const float4* row4 = (const float4*)(cb + (size_t)k * D_DIM);
    double a0 = 0.0, a1 = 0.0, a2 = 0.0, a3 = 0.0;
#pragma unroll
    for (int i = 0; i < 16; ++i) {
        float4 v = row4[i * 64 + lane];
        a0 += (double)v.x * v.x; a1 += (double)v.y * v.y;
        a2 += (double)v.z * v.z; a3 += (double)v.w * v.w;
        ushort4 h;
        h.x = f2bf(v.x); h.y = f2bf(v.y); h.z = f2bf(v.z); h.w = f2bf(v.w);
        const int c = (i * 64 + lane) * 4;               // col of this chunk
        const size_t idx = (((size_t)(c >> 5) * 16 + (k >> 4)) * 64
                            + ((c >> 3) & 3) * 16 + (k & 15)) * 8 + (c & 7);
        *(ushort4*)&cbsw[idx] = h;
    }
    double s = (a0 + a1) + (a2 + a3);
    for (int off = 32; off; off >>= 1) s += __shfl_xor(s, off);
    if (lane == 0) cc[k] = s;
}

// ---------------------------------------------------------------------------
// gemm_d2: v10's verified zero-barrier full-K GEMM, writing compact d2 (4 MB)
// + xxp instead of an in-block epilogue. 256 blocks x 512 threads (8 waves).
// Block = 16 rows x 256 codes x K=4096; A tile (128 KB) staged once in LDS.
// ---------------------------------------------------------------------------
__global__ __launch_bounds__(512) void gemm_d2(const float* __restrict__ x,
                                               const unsigned short* __restrict__ cbsw,
                                               float* __restrict__ d2,
                                               float* __restrict__ xxp) {
    __shared__ unsigned short As[NSTEP * 512];   // 128 KB full-K A tile
    const int t = threadIdx.x;
    const int lane = t & 63, w = t >> 6;         // 8 waves
    const int m0 = blockIdx.x * MT;

    // ---- stage full A tile: thread t -> row t>>5, cols (t&31)*4 + 128*p ----
    const int arow = t >> 5;                     // 0..15
    const int ac0 = (t & 31) * 4;                // 0..124
    const float4* ag4 = (const float4*)(x + (size_t)(m0 + arow) * D_DIM + ac0);
    float sq = 0.f;
#pragma unroll
    for (int p = 0; p < 32; ++p) {
        float4 v = ag4[(size_t)p * 32];
        ushort4 h;
        h.x = f2bf(v.x); h.y = f2bf(v.y); h.z = f2bf(v.z); h.w = f2bf(v.w);
        const int c = ac0 + p * 128;
        *(ushort4*)&As[(c >> 5) * 512 + (((c >> 3) & 3) * 16 + arow) * 8 + (c & 7)] = h;
        sq += v.x * v.x + v.y * v.y + v.z * v.z + v.w * v.w;
    }
    sq += __shfl_xor(sq, 1); sq += __shfl_xor(sq, 2); sq += __shfl_xor(sq, 4);
    sq += __shfl_xor(sq, 8); sq += __shfl_xor(sq, 16);
    if ((t & 31) == 0) xxp[m0 + arow] = sq;
    __syncthreads();                             // the only barrier

    // ---- streaming K-loop: no barriers ----
    f32x4 acc0 = {0.f, 0.f, 0.f, 0.f}, acc1 = {0.f, 0.f, 0.f, 0.f};
    const unsigned short* bb = cbsw + w * 1024 + lane * 8;
    const unsigned short* ar = &As[lane * 8];
#pragma unroll 8
    for (int s = 0; s < NSTEP; ++s) {
        bf16x8 af = *(const bf16x8*)(ar + s * 512);
        bf16x8 b0 = *(const bf16x8*)(bb + (size_t)s * 8192);
        bf16x8 b1 = *(const bf16x8*)(bb + (size_t)s * 8192 + 512);
        acc0 = __builtin_amdgcn_mfma_f32_16x16x32_bf16(af, b0, acc0, 0, 0, 0);
        acc1 = __builtin_amdgcn_mfma_f32_16x16x32_bf16(af, b1, acc1, 0, 0, 0);
    }

    // ---- write d2 (C/D: col=lane&15, row=(lane>>4)*4+r) ----
#pragma unroll
    for (int r = 0; r < 4; ++r) {
        const int orow = (lane >> 4) * 4 + r;
        float* dst = d2 + (size_t)(m0 + orow) * K_CODES + w * 32 + (lane & 15);
        dst[0]  = acc0[r];
        dst[16] = acc1[r];
    }
}

// ---------------------------------------------------------------------------
// finish: wave-per-row (1024 blocks x 256 = 4096 waves, full TLP).
// d2 read directly (1 KB/row), butterfly max, margin candidates; single
// candidate -> done; else exact f64 refinement (rare). Writes idx, loss,
// probs(=0), quant row. Structure verified in R1-R4.
// ---------------------------------------------------------------------------
__global__ __launch_bounds__(256) void finish(const float* __restrict__ x,
                                              const float* __restrict__ cb,
                                              const float* __restrict__ d2,
                                              const double* __restrict__ cc,
                                              const float* __restrict__ xxp,
                                              float* __restrict__ out) {
    const int lane = threadIdx.x & 63;
    const int row = blockIdx.x * 4 + (threadIdx.x >> 6);

    const double xx = (double)xxp[row];
    const float4 dv = ((const float4*)(d2 + (size_t)row * K_CODES))[lane];
    double v[4];
    v[0] = xx + cc[4 * lane + 0] - 2.0 * (double)dv.x;
    v[1] = xx + cc[4 * lane + 1] - 2.0 * (double)dv.y;
    v[2] = xx + cc[4 * lane + 2] - 2.0 * (double)dv.z;
    v[3] = xx + cc[4 * lane + 3] - 2.0 * (double)dv.w;

    double mx = fmax(fmax(v[0], v[1]), fmax(v[2], v[3]));
    for (int off = 32; off; off >>= 1) mx = fmax(mx, __shfl_xor(mx, off));
    const double thr = mx - MARGIN;

    unsigned long long b[4];
#pragma unroll
    for (int j = 0; j < 4; ++j) b[j] = __ballot(v[j] >= thr);
    const int total = __popcll(b[0]) + __popcll(b[1]) + __popcll(b[2]) + __popcll(b[3]);

    int bestk = 0; double best;
    if (total == 1) {
        best = mx;   // lone candidate IS the max; error bound guarantees argmax
#pragma unroll
        for (int j = 0; j < 4; ++j)
            if (b[j]) bestk = 4 * (int)__builtin_ctzll(b[j]) + j;
    } else {
        const float4* xrow4 = (const float4*)(x + (size_t)row * D_DIM);
        int flags = 0;
#pragma unroll
        for (int j = 0; j < 4; ++j) if (v[j] >= thr) flags |= 1 << j;
        unsigned long long cand = __ballot(flags != 0);
        best = -1.0e300;
        while (cand) {
            const int lsrc = __builtin_ctzll(cand);
            cand &= cand - 1;
            const int f = __shfl(flags, lsrc);
            for (int j = 0; j < 4; ++j) {
                if (!((f >> j) & 1)) continue;
                const int k = 4 * lsrc + j;
                const float4* crow4 = (const float4*)(cb + (size_t)k * D_DIM);
                double a0 = 0.0, a1 = 0.0, a2 = 0.0, a3 = 0.0;
#pragma unroll
                for (int i = 0; i < 16; ++i) {
                    float4 xa = xrow4[i * 64 + lane];
                    float4 ca = crow4[i * 64 + lane];
                    a0 += (double)xa.x * ca.x; a1 += (double)xa.y * ca.y;
                    a2 += (double)xa.z * ca.z; a3 += (double)xa.w * ca.w;
                }
                double s = (a0 + a1) + (a2 + a3);
                for (int off = 32; off; off >>= 1) s += __shfl_xor(s, off);
                const double d2e = xx + cc[k] - 2.0 * s;    // identical across lanes
                if (d2e > best) { best = d2e; bestk = k; }  // ascending k, strict >
            }
        }
    }

    if (lane == 0) {
        out[IDX_OFF + row]  = (float)bestk;
        out[LOSS_OFF + row] = (float)(1.25 * best / (double)D_DIM);
    }
    float4 z = make_float4(0.f, 0.f, 0.f, 0.f);
    ((float4*)(out + PROBS_OFF + (size_t)row * K_CODES))[lane] = z;
    const float4* src = (const float4*)(cb + (size_t)bestk * D_DIM);
    float4* dst = (float4*)(out + (size_t)row * D_DIM);
#pragma unroll
    for (int i = 0; i < 16; ++i) dst[i * 64 + lane] = src[i * 64 + lane];
}

// ---------------------------------------------------------------------------
extern "C" void kernel_launch(void* const* d_in, const int* in_sizes, int n_in,
                              void* d_out, int out_size, void* d_ws, size_t ws_size,
                              hipStream_t stream) {
    const float* x  = (const float*)d_in[0];
    const float* cb = (const float*)d_in[1];
    float* out = (float*)d_out;

    float*          d2   = (float*)d_ws;
    unsigned short* cbsw = (unsigned short*)((char*)d_ws + (size_t)B_ROWS * K_CODES * sizeof(float));
    double*         cc   = (double*)((char*)cbsw + (size_t)K_CODES * D_DIM * sizeof(unsigned short));
    float*          xxp  = (float*)(cc + K_CODES);

    hipLaunchKernelGGL(prep_cb, dim3(256),  dim3(64),  0, stream, cb, cbsw, cc);
    hipLaunchKernelGGL(gemm_d2, dim3(256),  dim3(512), 0, stream, x, cbsw, d2, xxp);
    hipLaunchKernelGGL(finish,  dim3(1024), dim3(256), 0, stream, x, cb, d2, cc, xxp, out);
}